// Round 4
// baseline (267.067 us; speedup 1.0000x reference)
//
#include <hip/hip_runtime.h>

typedef __attribute__((ext_vector_type(8))) short short8;
typedef __attribute__((ext_vector_type(4))) short short4v;
typedef __attribute__((ext_vector_type(4))) float f32x4;

__device__ __forceinline__ unsigned short f2bf(float f) {
  union { float f; unsigned u; } v; v.f = f;
  unsigned u = v.u;
  return (unsigned short)((u + 0x7fffu + ((u >> 16) & 1u)) >> 16);
}

__device__ __forceinline__ void gload16(void* lds, const void* g) {
  __builtin_amdgcn_global_load_lds(
      (__attribute__((address_space(1))) unsigned int*)g,
      (__attribute__((address_space(3))) unsigned int*)lds, 16, 0, 0);
}

// ---------------- cast x: fp32 -> bf16, 8 elems/thread ----------------
__global__ void cast_f32_bf16(const float* __restrict__ in,
                              unsigned short* __restrict__ out, int n8) {
  int i = blockIdx.x * 256 + threadIdx.x;
  if (i >= n8) return;
  const float4* p = (const float4*)in + (size_t)i * 2;
  float4 a = p[0], b = p[1];
  union { unsigned short u[8]; short8 v; } o;
  o.u[0] = f2bf(a.x); o.u[1] = f2bf(a.y); o.u[2] = f2bf(a.z); o.u[3] = f2bf(a.w);
  o.u[4] = f2bf(b.x); o.u[5] = f2bf(b.y); o.u[6] = f2bf(b.z); o.u[7] = f2bf(b.w);
  *(short8*)(out + (size_t)i * 8) = o.v;
}

// ------------- transpose+cast: W[K=2048][N] fp32 -> dst[N][2048] bf16 -------------
__global__ void trans_cast(const float* __restrict__ src,
                           unsigned short* __restrict__ dst,
                           int N, int rowOff) {
  __shared__ float tile[32][33];
  int n0 = blockIdx.x * 32, k0 = blockIdx.y * 32;
  int c = threadIdx.x & 31, rr = threadIdx.x >> 5;
#pragma unroll
  for (int p = 0; p < 4; ++p) {
    int r = p * 8 + rr;
    tile[r][c] = src[(size_t)(k0 + r) * N + n0 + c];
  }
  __syncthreads();
#pragma unroll
  for (int p = 0; p < 4; ++p) {
    int r = p * 8 + rr;
    dst[(size_t)(rowOff + n0 + r) * 2048 + k0 + c] = f2bf(tile[c][r]);
  }
}

// ---------------- GEMM: C[M][N] = A[M][K]bf16 @ Bt[N][K]bf16, BK=64 ----------------
__global__ __launch_bounds__(256) void gemm_bf16(
    const unsigned short* __restrict__ A, const unsigned short* __restrict__ Bt,
    int K, int mode,
    const float* __restrict__ b0, const float* __restrict__ b1,
    const float* __restrict__ b2,
    unsigned short* __restrict__ oq, unsigned short* __restrict__ ok,
    unsigned short* __restrict__ ov, float* __restrict__ of) {
  __shared__ unsigned short lds[16384];  // A [128][64] @0, B [128][64] @16KB
  int tid = threadIdx.x, w = tid >> 6, lane = tid & 63, lo = lane & 15, hi = lane >> 4;
  int wr = w >> 1, wc = w & 1;
  int m0 = blockIdx.x * 128, n0 = blockIdx.y * 128;
  f32x4 acc[4][4] = {};
  const char* Ab = (const char*)A;
  const char* Bb = (const char*)Bt;
  char* L = (char*)lds;

  for (int k0 = 0; k0 < K; k0 += 64) {
#pragma unroll
    for (int j = 0; j < 4; ++j) {
      int o = j * 4096 + w * 1024 + lane * 16;
      int r = o >> 7;
      gload16(L + j * 4096 + w * 1024,
              Ab + (size_t)(m0 + r) * K * 2 + k0 * 2 + (o & 127));
    }
#pragma unroll
    for (int j = 0; j < 4; ++j) {
      int o = j * 4096 + w * 1024 + lane * 16;
      int r = o >> 7;
      gload16(L + 16384 + j * 4096 + w * 1024,
              Bb + (size_t)(n0 + r) * K * 2 + k0 * 2 + (o & 127));
    }
    __syncthreads();
    short8 af[2][4], bf[2][4];
#pragma unroll
    for (int ks = 0; ks < 2; ++ks) {
#pragma unroll
      for (int i = 0; i < 4; ++i)
        af[ks][i] = *(const short8*)(L + (wr * 64 + i * 16 + lo) * 128 + ks * 64 + hi * 16);
#pragma unroll
      for (int j = 0; j < 4; ++j)
        bf[ks][j] = *(const short8*)(L + 16384 + (wc * 64 + j * 16 + lo) * 128 + ks * 64 + hi * 16);
    }
#pragma unroll
    for (int ks = 0; ks < 2; ++ks)
#pragma unroll
      for (int i = 0; i < 4; ++i)
#pragma unroll
        for (int j = 0; j < 4; ++j)
          acc[i][j] = __builtin_amdgcn_mfma_f32_16x16x32_bf16(af[ks][i], bf[ks][j], acc[i][j], 0, 0, 0);
    __syncthreads();
  }

  // epilogue; C/D layout: col = lane&15, row = (lane>>4)*4 + r  [verified m89]
  // Q scale folds 1/sqrt(128) AND log2(e) (attn softmax runs in exp2 domain)
#pragma unroll
  for (int i = 0; i < 4; ++i) {
    int mbase = m0 + wr * 64 + i * 16 + hi * 4;
#pragma unroll
    for (int j = 0; j < 4; ++j) {
      int n = n0 + wc * 64 + j * 16 + lo;
      if (mode == 0) {
        float bias;
        if (n < 2048) bias = b0[n];
        else if (n < 2560) bias = b1[n - 2048];
        else bias = b2[n - 2560];
#pragma unroll
        for (int r = 0; r < 4; ++r) {
          int mm = mbase + r;
          int b = mm >> 11, t = mm & 2047;
          float val = acc[i][j][r] + bias;
          if (n < 2048) {
            int h = n >> 7, d = n & 127;
            oq[(((size_t)(b * 16 + h)) * 2048 + t) * 128 + d] =
                f2bf(val * (0.08838834764831845f * 1.4426950408889634f));
          } else if (n < 2560) {
            int kvh = (n - 2048) >> 7, d = (n - 2048) & 127;
            ok[(((size_t)(b * 4 + kvh)) * 2048 + t) * 128 + d] = f2bf(val);
          } else {
            int kvh = (n - 2560) >> 7, d = (n - 2560) & 127;
            ov[(((size_t)(b * 4 + kvh)) * 128 + d) * 2048 + t] = f2bf(val);
          }
        }
      } else {
        float bias = b0[n];
#pragma unroll
        for (int r = 0; r < 4; ++r)
          of[(size_t)(mbase + r) * 2048 + n] = acc[i][j][r] + bias;
      }
    }
  }
}

// ---------------- flash attention (swapped QK^T, KVBLK=64, dbuf, defer-max) ----------------
__device__ __forceinline__ void stageK(char* KLb, const char* kcb, int w, int lane, int t0) {
#pragma unroll
  for (int j = 0; j < 4; ++j) {
    int o = j * 4096 + w * 1024 + lane * 16;
    int row = o >> 8;
    gload16(KLb + j * 4096 + w * 1024, kcb + t0 * 256 + (o ^ ((row & 7) << 4)));
  }
}
__device__ __forceinline__ void stageV(char* VLb, const char* vcb, int w, int lane, int t0) {
#pragma unroll
  for (int j = 0; j < 4; ++j) {
    int o = j * 4096 + w * 1024 + lane * 16;
    int d = o >> 7, low = o & 127;
    gload16(VLb + j * 4096 + w * 1024,
            vcb + (size_t)d * 4096 + t0 * 2 + (low ^ ((d & 7) << 4)));
  }
}

// q[B,H,T,128] (pre-scaled by 1/sqrt(d)*log2e), k[B,KV,T,128], vt[B,KV,128,T]
// out attn[B,T,H*128] bf16; softmax in exp2 domain, defer-max THR=8
__global__ __launch_bounds__(256, 2) void attn_fwd(
    const unsigned short* __restrict__ q, const unsigned short* __restrict__ kg,
    const unsigned short* __restrict__ vtg, unsigned short* __restrict__ attn) {
  __shared__ unsigned short kbuf[16384];  // 2 x [64 kv][128 d], rows 256B, swz ((kv&7)<<4)
  __shared__ unsigned short vbuf[16384];  // 2 x [128 d][64 kv], rows 128B, swz ((d&7)<<4)
  __shared__ unsigned short pbuf[8192];   // 4 waves x [32 q][64 kv], rows 128B, swz ((q&7)<<4)
  int tid = threadIdx.x, w = tid >> 6, lane = tid & 63, lo = lane & 15, hi = lane >> 4;
  int tq0 = blockIdx.x * 128, h = blockIdx.y, b = blockIdx.z, kvh = h >> 2;
  int qrow = tq0 + w * 32;

  const unsigned short* qbase = q + ((size_t)(b * 16 + h)) * 2048 * 128;
  short8 qf[2][4];
#pragma unroll
  for (int j2 = 0; j2 < 2; ++j2)
#pragma unroll
    for (int ks = 0; ks < 4; ++ks)
      qf[j2][ks] = *(const short8*)(qbase + (size_t)(qrow + j2 * 16 + lo) * 128 + ks * 32 + hi * 8);

  f32x4 oacc[2][8] = {};
  float mrow[2] = {-1e30f, -1e30f}, lsum[2] = {0.f, 0.f};

  const char* kcb = (const char*)(kg + ((size_t)(b * 4 + kvh)) * 2048 * 128);
  const char* vcb = (const char*)(vtg + ((size_t)(b * 4 + kvh)) * 128 * 2048);
  char* KL = (char*)kbuf;
  char* VL = (char*)vbuf;
  char* PL = (char*)pbuf + w * 4096;

  stageK(KL, kcb, w, lane, 0);
  stageV(VL, vcb, w, lane, 0);
  __syncthreads();
  int buf = 0;

  for (int t0 = 0; t0 < 2048; t0 += 64) {
    if (t0 + 64 < 2048) {  // prefetch next chunk into other buffer
      stageK(KL + (buf ^ 1) * 16384, kcb, w, lane, t0 + 64);
      stageV(VL + (buf ^ 1) * 16384, vcb, w, lane, t0 + 64);
    }
    const char* KB = KL + buf * 16384;
    const char* VB = VL + buf * 16384;

    // S^T = K Q^T : C col = q (lo), row = kv (hi*4+r); s[f][j2], kv = f*16+hi*4+r
    f32x4 s[4][2] = {};
    __builtin_amdgcn_s_setprio(1);
#pragma unroll
    for (int f = 0; f < 4; ++f) {
      int row = f * 16 + lo;
      int sw = (row & 7) << 4;
#pragma unroll
      for (int ks = 0; ks < 4; ++ks) {
        short8 kf = *(const short8*)(KB + ((row * 256 + ks * 64 + hi * 16) ^ sw));
#pragma unroll
        for (int j2 = 0; j2 < 2; ++j2)
          s[f][j2] = __builtin_amdgcn_mfma_f32_16x16x32_bf16(kf, qf[j2][ks], s[f][j2], 0, 0, 0);
      }
    }
    __builtin_amdgcn_s_setprio(0);

    // chunk-local max per lane (16 kv values per j2)
    float a[2];
#pragma unroll
    for (int j2 = 0; j2 < 2; ++j2) {
      float a0 = fmaxf(fmaxf(s[0][j2][0], s[0][j2][1]), fmaxf(s[0][j2][2], s[0][j2][3]));
      float a1 = fmaxf(fmaxf(s[1][j2][0], s[1][j2][1]), fmaxf(s[1][j2][2], s[1][j2][3]));
      float a2 = fmaxf(fmaxf(s[2][j2][0], s[2][j2][1]), fmaxf(s[2][j2][2], s[2][j2][3]));
      float a3 = fmaxf(fmaxf(s[3][j2][0], s[3][j2][1]), fmaxf(s[3][j2][2], s[3][j2][3]));
      a[j2] = fmaxf(fmaxf(a0, a1), fmaxf(a2, a3));
    }
    // defer-max: only rescale when some lane's chunk max exceeds m+8 (log2 domain)
    int okv = (a[0] <= mrow[0] + 8.f) && (a[1] <= mrow[1] + 8.f);
    if (!__all(okv)) {
      float fs[2];
#pragma unroll
      for (int j2 = 0; j2 < 2; ++j2) {
        float am = a[j2];
        am = fmaxf(am, __shfl_xor(am, 16));
        am = fmaxf(am, __shfl_xor(am, 32));
        float mnew = fmaxf(mrow[j2], am);
        fs[j2] = __builtin_amdgcn_exp2f(mrow[j2] - mnew);
        mrow[j2] = mnew;
        lsum[j2] *= fs[j2];
      }
#pragma unroll
      for (int i = 0; i < 2; ++i)
#pragma unroll
        for (int r = 0; r < 4; ++r) {
          float fsr = __shfl(fs[i], hi * 4 + r);
#pragma unroll
          for (int nf = 0; nf < 8; ++nf) oacc[i][nf][r] *= fsr;
        }
    }

    // P = exp2(S - m), pack to bf16 (known-good manual pack), store to per-wave LDS
#pragma unroll
    for (int j2 = 0; j2 < 2; ++j2) {
      int qq = j2 * 16 + lo;
      int sw = (qq & 7) << 4;
      float m = mrow[j2];
      float acc = 0.f;
#pragma unroll
      for (int f = 0; f < 4; ++f) {
        float p0 = __builtin_amdgcn_exp2f(s[f][j2][0] - m);
        float p1 = __builtin_amdgcn_exp2f(s[f][j2][1] - m);
        float p2 = __builtin_amdgcn_exp2f(s[f][j2][2] - m);
        float p3 = __builtin_amdgcn_exp2f(s[f][j2][3] - m);
        union { unsigned short u[4]; short4v v; } pk;
        pk.u[0] = f2bf(p0); pk.u[1] = f2bf(p1); pk.u[2] = f2bf(p2); pk.u[3] = f2bf(p3);
        *(short4v*)(PL + ((qq * 128 + f * 32 + hi * 8) ^ sw)) = pk.v;
        acc += (p0 + p1) + (p2 + p3);
      }
      lsum[j2] += acc;  // per-lane partial; reduced across hi in epilogue
    }
    __threadfence_block();  // order P ds_writes before A-frag reads (per-wave buffer)

    // O += P V : A = P[q][kv], B = V^T[d][kv]
    short8 pfr[2][2];
#pragma unroll
    for (int i = 0; i < 2; ++i) {
      int qq = i * 16 + lo;
      int sw = (qq & 7) << 4;
#pragma unroll
      for (int ks2 = 0; ks2 < 2; ++ks2)
        pfr[i][ks2] = *(const short8*)(PL + ((qq * 128 + ks2 * 64 + hi * 16) ^ sw));
    }
    __builtin_amdgcn_s_setprio(1);
#pragma unroll
    for (int nf = 0; nf < 8; ++nf) {
      int d = nf * 16 + lo;
      int sw = (d & 7) << 4;
#pragma unroll
      for (int ks2 = 0; ks2 < 2; ++ks2) {
        short8 vf = *(const short8*)(VB + ((d * 128 + ks2 * 64 + hi * 16) ^ sw));
#pragma unroll
        for (int i = 0; i < 2; ++i)
          oacc[i][nf] = __builtin_amdgcn_mfma_f32_16x16x32_bf16(pfr[i][ks2], vf, oacc[i][nf], 0, 0, 0);
      }
    }
    __builtin_amdgcn_s_setprio(0);
    __syncthreads();
    buf ^= 1;
  }

  // epilogue: reduce lsum across hi groups, then attn[b][t][h*128 + d]
  unsigned short* ob = attn + ((size_t)b * 2048) * 2048 + h * 128;
#pragma unroll
  for (int i = 0; i < 2; ++i) {
    float ls = lsum[i];
    ls += __shfl_xor(ls, 16);
    ls += __shfl_xor(ls, 32);
    float linv = 1.0f / ls;
#pragma unroll
    for (int r = 0; r < 4; ++r) {
      float lr = __shfl(linv, hi * 4 + r);
      int t = qrow + i * 16 + hi * 4 + r;
#pragma unroll
      for (int nf = 0; nf < 8; ++nf)
        ob[(size_t)t * 2048 + nf * 16 + lo] = f2bf(oacc[i][nf][r] * lr);
    }
  }
}

extern "C" void kernel_launch(void* const* d_in, const int* in_sizes, int n_in,
                              void* d_out, int out_size, void* d_ws, size_t ws_size,
                              hipStream_t stream) {
  const float* x  = (const float*)d_in[0];
  // d_in[1] = mask (all-True, unused)
  const float* Wq = (const float*)d_in[2];
  const float* bq = (const float*)d_in[3];
  const float* Wk = (const float*)d_in[4];
  const float* bk = (const float*)d_in[5];
  const float* Wv = (const float*)d_in[6];
  const float* bv = (const float*)d_in[7];
  const float* Wo = (const float*)d_in[8];
  const float* bo = (const float*)d_in[9];
  float* out = (float*)d_out;

  char* ws = (char*)d_ws;
  unsigned short* xb    = (unsigned short*)(ws);                        // 16.78 MB
  unsigned short* wqkvT = (unsigned short*)(ws + 16777216);             // 12.58 MB
  unsigned short* woT   = (unsigned short*)(ws + 29360128);             //  8.39 MB
  unsigned short* qb    = (unsigned short*)(ws + 37748736);             // 16.78 MB
  unsigned short* kbw   = (unsigned short*)(ws + 54525952);             //  4.19 MB
  unsigned short* vtw   = (unsigned short*)(ws + 58720256);             //  4.19 MB
  unsigned short* attnb = (unsigned short*)(ws + 62914560);             // 16.78 MB

  cast_f32_bf16<<<dim3(4096), dim3(256), 0, stream>>>(x, xb, 1048576);
  trans_cast<<<dim3(64, 64), dim3(256), 0, stream>>>(Wq, wqkvT, 2048, 0);
  trans_cast<<<dim3(16, 64), dim3(256), 0, stream>>>(Wk, wqkvT, 512, 2048);
  trans_cast<<<dim3(16, 64), dim3(256), 0, stream>>>(Wv, wqkvT, 512, 2560);
  trans_cast<<<dim3(64, 64), dim3(256), 0, stream>>>(Wo, woT, 2048, 0);

  // fused QKV projection: M=4096, N=3072, K=2048
  gemm_bf16<<<dim3(32, 24), dim3(256), 0, stream>>>(
      xb, wqkvT, 2048, 0, bq, bk, bv, qb, kbw, vtw, nullptr);

  attn_fwd<<<dim3(16, 16, 2), dim3(256), 0, stream>>>(qb, kbw, vtw, attnb);

  // output projection: M=4096, N=2048, K=2048 -> fp32 out + bo
  gemm_bf16<<<dim3(32, 16), dim3(256), 0, stream>>>(
      attnb, woT, 2048, 1, bo, nullptr, nullptr, nullptr, nullptr, nullptr, out);
}

// Round 5
// 243.714 us; speedup vs baseline: 1.0958x; 1.0958x over previous
//
#include <hip/hip_runtime.h>

typedef __attribute__((ext_vector_type(8))) short short8;
typedef __attribute__((ext_vector_type(4))) short short4v;
typedef __attribute__((ext_vector_type(4))) float f32x4;

__device__ __forceinline__ unsigned short f2bf(float f) {
  union { float f; unsigned u; } v; v.f = f;
  unsigned u = v.u;
  return (unsigned short)((u + 0x7fffu + ((u >> 16) & 1u)) >> 16);
}

__device__ __forceinline__ void gload16(void* lds, const void* g) {
  __builtin_amdgcn_global_load_lds(
      (__attribute__((address_space(1))) unsigned int*)g,
      (__attribute__((address_space(3))) unsigned int*)lds, 16, 0, 0);
}

// ---------------- cast x: fp32 -> bf16, 8 elems/thread ----------------
__global__ void cast_f32_bf16(const float* __restrict__ in,
                              unsigned short* __restrict__ out, int n8) {
  int i = blockIdx.x * 256 + threadIdx.x;
  if (i >= n8) return;
  const float4* p = (const float4*)in + (size_t)i * 2;
  float4 a = p[0], b = p[1];
  union { unsigned short u[8]; short8 v; } o;
  o.u[0] = f2bf(a.x); o.u[1] = f2bf(a.y); o.u[2] = f2bf(a.z); o.u[3] = f2bf(a.w);
  o.u[4] = f2bf(b.x); o.u[5] = f2bf(b.y); o.u[6] = f2bf(b.z); o.u[7] = f2bf(b.w);
  *(short8*)(out + (size_t)i * 8) = o.v;
}

// ------------- transpose+cast: W[K=2048][N] fp32 -> dst[N][2048] bf16 -------------
__global__ void trans_cast(const float* __restrict__ src,
                           unsigned short* __restrict__ dst,
                           int N, int rowOff) {
  __shared__ float tile[32][33];
  int n0 = blockIdx.x * 32, k0 = blockIdx.y * 32;
  int c = threadIdx.x & 31, rr = threadIdx.x >> 5;
#pragma unroll
  for (int p = 0; p < 4; ++p) {
    int r = p * 8 + rr;
    tile[r][c] = src[(size_t)(k0 + r) * N + n0 + c];
  }
  __syncthreads();
#pragma unroll
  for (int p = 0; p < 4; ++p) {
    int r = p * 8 + rr;
    dst[(size_t)(rowOff + n0 + r) * 2048 + k0 + c] = f2bf(tile[c][r]);
  }
}

// ---------------- GEMM: C[M][N] = A[M][K]bf16 @ Bt[N][K]bf16, BK=64, XOR-swizzled LDS ----------------
__global__ __launch_bounds__(256) void gemm_bf16(
    const unsigned short* __restrict__ A, const unsigned short* __restrict__ Bt,
    int K, int mode,
    const float* __restrict__ b0, const float* __restrict__ b1,
    const float* __restrict__ b2,
    unsigned short* __restrict__ oq, unsigned short* __restrict__ ok,
    unsigned short* __restrict__ ov, float* __restrict__ of) {
  __shared__ unsigned short lds[16384];  // A [128][64] @0, B [128][64] @16KB; swz byte^((row&7)<<4)
  int tid = threadIdx.x, w = tid >> 6, lane = tid & 63, lo = lane & 15, hi = lane >> 4;
  int wr = w >> 1, wc = w & 1;
  int m0 = blockIdx.x * 128, n0 = blockIdx.y * 128;
  f32x4 acc[4][4] = {};
  const char* Ab = (const char*)A;
  const char* Bb = (const char*)Bt;
  char* L = (char*)lds;

  for (int k0 = 0; k0 < K; k0 += 64) {
    // stage: linear LDS dest, inverse-swizzled global source (rule 21)
#pragma unroll
    for (int j = 0; j < 4; ++j) {
      int o = j * 4096 + w * 1024 + lane * 16;
      int r = o >> 7;
      int cb = (o & 127) ^ ((r & 7) << 4);
      gload16(L + j * 4096 + w * 1024,
              Ab + (size_t)(m0 + r) * K * 2 + k0 * 2 + cb);
    }
#pragma unroll
    for (int j = 0; j < 4; ++j) {
      int o = j * 4096 + w * 1024 + lane * 16;
      int r = o >> 7;
      int cb = (o & 127) ^ ((r & 7) << 4);
      gload16(L + 16384 + j * 4096 + w * 1024,
              Bb + (size_t)(n0 + r) * K * 2 + k0 * 2 + cb);
    }
    __syncthreads();
    short8 af[2][4], bf[2][4];
#pragma unroll
    for (int ks = 0; ks < 2; ++ks) {
#pragma unroll
      for (int i = 0; i < 4; ++i) {
        int row = wr * 64 + i * 16 + lo;
        af[ks][i] = *(const short8*)(L + ((row * 128 + ks * 64 + hi * 16) ^ ((row & 7) << 4)));
      }
#pragma unroll
      for (int j = 0; j < 4; ++j) {
        int row = wc * 64 + j * 16 + lo;
        bf[ks][j] = *(const short8*)(L + 16384 + ((row * 128 + ks * 64 + hi * 16) ^ ((row & 7) << 4)));
      }
    }
#pragma unroll
    for (int ks = 0; ks < 2; ++ks)
#pragma unroll
      for (int i = 0; i < 4; ++i)
#pragma unroll
        for (int j = 0; j < 4; ++j)
          acc[i][j] = __builtin_amdgcn_mfma_f32_16x16x32_bf16(af[ks][i], bf[ks][j], acc[i][j], 0, 0, 0);
    __syncthreads();
  }

  // epilogue; C/D layout: col = lane&15, row = (lane>>4)*4 + r  [verified m89]
  // Q scale folds 1/sqrt(128) AND log2(e) (attn softmax runs in exp2 domain)
#pragma unroll
  for (int i = 0; i < 4; ++i) {
    int mbase = m0 + wr * 64 + i * 16 + hi * 4;
#pragma unroll
    for (int j = 0; j < 4; ++j) {
      int n = n0 + wc * 64 + j * 16 + lo;
      if (mode == 0) {
        float bias;
        if (n < 2048) bias = b0[n];
        else if (n < 2560) bias = b1[n - 2048];
        else bias = b2[n - 2560];
#pragma unroll
        for (int r = 0; r < 4; ++r) {
          int mm = mbase + r;
          int b = mm >> 11, t = mm & 2047;
          float val = acc[i][j][r] + bias;
          if (n < 2048) {
            int h = n >> 7, d = n & 127;
            oq[(((size_t)(b * 16 + h)) * 2048 + t) * 128 + d] =
                f2bf(val * (0.08838834764831845f * 1.4426950408889634f));
          } else if (n < 2560) {
            int kvh = (n - 2048) >> 7, d = (n - 2048) & 127;
            ok[(((size_t)(b * 4 + kvh)) * 2048 + t) * 128 + d] = f2bf(val);
          } else {
            int kvh = (n - 2560) >> 7, d = (n - 2560) & 127;
            ov[(((size_t)(b * 4 + kvh)) * 128 + d) * 2048 + t] = f2bf(val);
          }
        }
      } else {
        float bias = b0[n];
#pragma unroll
        for (int r = 0; r < 4; ++r)
          of[(size_t)(mbase + r) * 2048 + n] = acc[i][j][r] + bias;
      }
    }
  }
}

// ---------------- flash attention (swapped QK^T, KVBLK=64, dbuf, defer-max) ----------------
__device__ __forceinline__ void stageK(char* KLb, const char* kcb, int w, int lane, int t0) {
#pragma unroll
  for (int j = 0; j < 4; ++j) {
    int o = j * 4096 + w * 1024 + lane * 16;
    int row = o >> 8;
    gload16(KLb + j * 4096 + w * 1024, kcb + t0 * 256 + (o ^ ((row & 7) << 4)));
  }
}
__device__ __forceinline__ void stageV(char* VLb, const char* vcb, int w, int lane, int t0) {
#pragma unroll
  for (int j = 0; j < 4; ++j) {
    int o = j * 4096 + w * 1024 + lane * 16;
    int d = o >> 7, low = o & 127;
    gload16(VLb + j * 4096 + w * 1024,
            vcb + (size_t)d * 4096 + t0 * 2 + (low ^ ((d & 7) << 4)));
  }
}

// q[B,H,T,128] (pre-scaled by 1/sqrt(d)*log2e), k[B,KV,T,128], vt[B,KV,128,T]
// out attn[B,T,H*128] bf16; softmax in exp2 domain, defer-max THR=8
__global__ __launch_bounds__(256, 2) void attn_fwd(
    const unsigned short* __restrict__ q, const unsigned short* __restrict__ kg,
    const unsigned short* __restrict__ vtg, unsigned short* __restrict__ attn) {
  __shared__ unsigned short kbuf[16384];  // 2 x [64 kv][128 d], rows 256B, swz ((kv&7)<<4)
  __shared__ unsigned short vbuf[16384];  // 2 x [128 d][64 kv], rows 128B, swz ((d&7)<<4)
  __shared__ unsigned short pbuf[8192];   // 4 waves x [32 q][64 kv], rows 128B, swz ((q&7)<<4)
  int tid = threadIdx.x, w = tid >> 6, lane = tid & 63, lo = lane & 15, hi = lane >> 4;
  int tq0 = blockIdx.x * 128, h = blockIdx.y, b = blockIdx.z, kvh = h >> 2;
  int qrow = tq0 + w * 32;

  const unsigned short* qbase = q + ((size_t)(b * 16 + h)) * 2048 * 128;
  short8 qf[2][4];
#pragma unroll
  for (int j2 = 0; j2 < 2; ++j2)
#pragma unroll
    for (int ks = 0; ks < 4; ++ks)
      qf[j2][ks] = *(const short8*)(qbase + (size_t)(qrow + j2 * 16 + lo) * 128 + ks * 32 + hi * 8);

  f32x4 oacc[2][8] = {};
  float mrow[2] = {-1e30f, -1e30f}, lsum[2] = {0.f, 0.f};

  const char* kcb = (const char*)(kg + ((size_t)(b * 4 + kvh)) * 2048 * 128);
  const char* vcb = (const char*)(vtg + ((size_t)(b * 4 + kvh)) * 128 * 2048);
  char* KL = (char*)kbuf;
  char* VL = (char*)vbuf;
  char* PL = (char*)pbuf + w * 4096;

  stageK(KL, kcb, w, lane, 0);
  stageV(VL, vcb, w, lane, 0);
  __syncthreads();
  int buf = 0;

  for (int t0 = 0; t0 < 2048; t0 += 64) {
    if (t0 + 64 < 2048) {  // prefetch next chunk into other buffer
      stageK(KL + (buf ^ 1) * 16384, kcb, w, lane, t0 + 64);
      stageV(VL + (buf ^ 1) * 16384, vcb, w, lane, t0 + 64);
    }
    const char* KB = KL + buf * 16384;
    const char* VB = VL + buf * 16384;

    // S^T = K Q^T : C col = q (lo), row = kv (hi*4+r); s[f][j2], kv = f*16+hi*4+r
    f32x4 s[4][2] = {};
    __builtin_amdgcn_s_setprio(1);
#pragma unroll
    for (int f = 0; f < 4; ++f) {
      int row = f * 16 + lo;
      int sw = (row & 7) << 4;
#pragma unroll
      for (int ks = 0; ks < 4; ++ks) {
        short8 kf = *(const short8*)(KB + ((row * 256 + ks * 64 + hi * 16) ^ sw));
#pragma unroll
        for (int j2 = 0; j2 < 2; ++j2)
          s[f][j2] = __builtin_amdgcn_mfma_f32_16x16x32_bf16(kf, qf[j2][ks], s[f][j2], 0, 0, 0);
      }
    }
    __builtin_amdgcn_s_setprio(0);

    // chunk-local max per lane (16 kv values per j2)
    float a[2];
#pragma unroll
    for (int j2 = 0; j2 < 2; ++j2) {
      float a0 = fmaxf(fmaxf(s[0][j2][0], s[0][j2][1]), fmaxf(s[0][j2][2], s[0][j2][3]));
      float a1 = fmaxf(fmaxf(s[1][j2][0], s[1][j2][1]), fmaxf(s[1][j2][2], s[1][j2][3]));
      float a2 = fmaxf(fmaxf(s[2][j2][0], s[2][j2][1]), fmaxf(s[2][j2][2], s[2][j2][3]));
      float a3 = fmaxf(fmaxf(s[3][j2][0], s[3][j2][1]), fmaxf(s[3][j2][2], s[3][j2][3]));
      a[j2] = fmaxf(fmaxf(a0, a1), fmaxf(a2, a3));
    }
    // defer-max: only rescale when some lane's chunk max exceeds m+8 (log2 domain)
    int okv = (a[0] <= mrow[0] + 8.f) && (a[1] <= mrow[1] + 8.f);
    if (!__all(okv)) {
      float fs[2];
#pragma unroll
      for (int j2 = 0; j2 < 2; ++j2) {
        float am = a[j2];
        am = fmaxf(am, __shfl_xor(am, 16));
        am = fmaxf(am, __shfl_xor(am, 32));
        float mnew = fmaxf(mrow[j2], am);
        fs[j2] = __builtin_amdgcn_exp2f(mrow[j2] - mnew);
        mrow[j2] = mnew;
        lsum[j2] *= fs[j2];
      }
#pragma unroll
      for (int i = 0; i < 2; ++i)
#pragma unroll
        for (int r = 0; r < 4; ++r) {
          float fsr = __shfl(fs[i], hi * 4 + r);
#pragma unroll
          for (int nf = 0; nf < 8; ++nf) oacc[i][nf][r] *= fsr;
        }
    }

    // P = exp2(S - m), pack to bf16 (known-good manual pack), store to per-wave LDS
#pragma unroll
    for (int j2 = 0; j2 < 2; ++j2) {
      int qq = j2 * 16 + lo;
      int sw = (qq & 7) << 4;
      float m = mrow[j2];
      float acc = 0.f;
#pragma unroll
      for (int f = 0; f < 4; ++f) {
        float p0 = __builtin_amdgcn_exp2f(s[f][j2][0] - m);
        float p1 = __builtin_amdgcn_exp2f(s[f][j2][1] - m);
        float p2 = __builtin_amdgcn_exp2f(s[f][j2][2] - m);
        float p3 = __builtin_amdgcn_exp2f(s[f][j2][3] - m);
        union { unsigned short u[4]; short4v v; } pk;
        pk.u[0] = f2bf(p0); pk.u[1] = f2bf(p1); pk.u[2] = f2bf(p2); pk.u[3] = f2bf(p3);
        *(short4v*)(PL + ((qq * 128 + f * 32 + hi * 8) ^ sw)) = pk.v;
        acc += (p0 + p1) + (p2 + p3);
      }
      lsum[j2] += acc;  // per-lane partial; reduced across hi in epilogue
    }
    __threadfence_block();  // order P ds_writes before A-frag reads (per-wave buffer)

    // O += P V : A = P[q][kv], B = V^T[d][kv]
    short8 pfr[2][2];
#pragma unroll
    for (int i = 0; i < 2; ++i) {
      int qq = i * 16 + lo;
      int sw = (qq & 7) << 4;
#pragma unroll
      for (int ks2 = 0; ks2 < 2; ++ks2)
        pfr[i][ks2] = *(const short8*)(PL + ((qq * 128 + ks2 * 64 + hi * 16) ^ sw));
    }
    __builtin_amdgcn_s_setprio(1);
#pragma unroll
    for (int nf = 0; nf < 8; ++nf) {
      int d = nf * 16 + lo;
      int sw = (d & 7) << 4;
#pragma unroll
      for (int ks2 = 0; ks2 < 2; ++ks2) {
        short8 vf = *(const short8*)(VB + ((d * 128 + ks2 * 64 + hi * 16) ^ sw));
#pragma unroll
        for (int i = 0; i < 2; ++i)
          oacc[i][nf] = __builtin_amdgcn_mfma_f32_16x16x32_bf16(pfr[i][ks2], vf, oacc[i][nf], 0, 0, 0);
      }
    }
    __builtin_amdgcn_s_setprio(0);
    __syncthreads();
    buf ^= 1;
  }

  // epilogue: reduce lsum across hi groups, then attn[b][t][h*128 + d]
  unsigned short* ob = attn + ((size_t)b * 2048) * 2048 + h * 128;
#pragma unroll
  for (int i = 0; i < 2; ++i) {
    float ls = lsum[i];
    ls += __shfl_xor(ls, 16);
    ls += __shfl_xor(ls, 32);
    float linv = 1.0f / ls;
#pragma unroll
    for (int r = 0; r < 4; ++r) {
      float lr = __shfl(linv, hi * 4 + r);
      int t = qrow + i * 16 + hi * 4 + r;
#pragma unroll
      for (int nf = 0; nf < 8; ++nf)
        ob[(size_t)t * 2048 + nf * 16 + lo] = f2bf(oacc[i][nf][r] * lr);
    }
  }
}

extern "C" void kernel_launch(void* const* d_in, const int* in_sizes, int n_in,
                              void* d_out, int out_size, void* d_ws, size_t ws_size,
                              hipStream_t stream) {
  const float* x  = (const float*)d_in[0];
  // d_in[1] = mask (all-True, unused)
  const float* Wq = (const float*)d_in[2];
  const float* bq = (const float*)d_in[3];
  const float* Wk = (const float*)d_in[4];
  const float* bk = (const float*)d_in[5];
  const float* Wv = (const float*)d_in[6];
  const float* bv = (const float*)d_in[7];
  const float* Wo = (const float*)d_in[8];
  const float* bo = (const float*)d_in[9];
  float* out = (float*)d_out;

  char* ws = (char*)d_ws;
  unsigned short* xb    = (unsigned short*)(ws);                        // 16.78 MB
  unsigned short* wqkvT = (unsigned short*)(ws + 16777216);             // 12.58 MB
  unsigned short* woT   = (unsigned short*)(ws + 29360128);             //  8.39 MB
  unsigned short* qb    = (unsigned short*)(ws + 37748736);             // 16.78 MB
  unsigned short* kbw   = (unsigned short*)(ws + 54525952);             //  4.19 MB
  unsigned short* vtw   = (unsigned short*)(ws + 58720256);             //  4.19 MB
  unsigned short* attnb = (unsigned short*)(ws + 62914560);             // 16.78 MB

  cast_f32_bf16<<<dim3(4096), dim3(256), 0, stream>>>(x, xb, 1048576);
  trans_cast<<<dim3(64, 64), dim3(256), 0, stream>>>(Wq, wqkvT, 2048, 0);
  trans_cast<<<dim3(16, 64), dim3(256), 0, stream>>>(Wk, wqkvT, 512, 2048);
  trans_cast<<<dim3(16, 64), dim3(256), 0, stream>>>(Wv, wqkvT, 512, 2560);
  trans_cast<<<dim3(64, 64), dim3(256), 0, stream>>>(Wo, woT, 2048, 0);

  // fused QKV projection: M=4096, N=3072, K=2048
  gemm_bf16<<<dim3(32, 24), dim3(256), 0, stream>>>(
      xb, wqkvT, 2048, 0, bq, bk, bv, qb, kbw, vtw, nullptr);

  attn_fwd<<<dim3(16, 16, 2), dim3(256), 0, stream>>>(qb, kbw, vtw, attnb);

  // output projection: M=4096, N=2048, K=2048 -> fp32 out + bo
  gemm_bf16<<<dim3(32, 16), dim3(256), 0, stream>>>(
      attnb, woT, 2048, 1, bo, nullptr, nullptr, nullptr, nullptr, nullptr, out);
}

// Round 6
// 241.636 us; speedup vs baseline: 1.1052x; 1.0086x over previous
//
#include <hip/hip_runtime.h>
#include <hip/hip_bf16.h>

typedef __attribute__((ext_vector_type(8))) short short8;
typedef __attribute__((ext_vector_type(4))) short short4v;
typedef __attribute__((ext_vector_type(4))) float f32x4;
typedef __attribute__((ext_vector_type(16))) float f32x16;
typedef __attribute__((ext_vector_type(2))) unsigned uint2v;

__device__ __forceinline__ unsigned short f2bf(float f) {
  union { float f; unsigned u; } v; v.f = f;
  unsigned u = v.u;
  return (unsigned short)((u + 0x7fffu + ((u >> 16) & 1u)) >> 16);
}

__device__ __forceinline__ unsigned packbf2(float a, float b) {
  union { __hip_bfloat162 h; unsigned u; } c;
  c.h = __float22bfloat162_rn(float2{a, b});
  return c.u;
}

__device__ __forceinline__ void gload16(void* lds, const void* g) {
  __builtin_amdgcn_global_load_lds(
      (__attribute__((address_space(1))) unsigned int*)g,
      (__attribute__((address_space(3))) unsigned int*)lds, 16, 0, 0);
}

// ---------------- cast x: fp32 -> bf16, 8 elems/thread ----------------
__global__ void cast_f32_bf16(const float* __restrict__ in,
                              unsigned short* __restrict__ out, int n8) {
  int i = blockIdx.x * 256 + threadIdx.x;
  if (i >= n8) return;
  const float4* p = (const float4*)in + (size_t)i * 2;
  float4 a = p[0], b = p[1];
  union { unsigned short u[8]; short8 v; } o;
  o.u[0] = f2bf(a.x); o.u[1] = f2bf(a.y); o.u[2] = f2bf(a.z); o.u[3] = f2bf(a.w);
  o.u[4] = f2bf(b.x); o.u[5] = f2bf(b.y); o.u[6] = f2bf(b.z); o.u[7] = f2bf(b.w);
  *(short8*)(out + (size_t)i * 8) = o.v;
}

// ------------- transpose+cast: W[K=2048][N] fp32 -> dst[N][2048] bf16 -------------
__global__ void trans_cast(const float* __restrict__ src,
                           unsigned short* __restrict__ dst,
                           int N, int rowOff) {
  __shared__ float tile[32][33];
  int n0 = blockIdx.x * 32, k0 = blockIdx.y * 32;
  int c = threadIdx.x & 31, rr = threadIdx.x >> 5;
#pragma unroll
  for (int p = 0; p < 4; ++p) {
    int r = p * 8 + rr;
    tile[r][c] = src[(size_t)(k0 + r) * N + n0 + c];
  }
  __syncthreads();
#pragma unroll
  for (int p = 0; p < 4; ++p) {
    int r = p * 8 + rr;
    dst[(size_t)(rowOff + n0 + r) * 2048 + k0 + c] = f2bf(tile[c][r]);
  }
}

// ---------------- GEMM: C[M][N] = A[M][K]bf16 @ Bt[N][K]bf16, BK=64, XOR-swizzled LDS ----------------
__global__ __launch_bounds__(256) void gemm_bf16(
    const unsigned short* __restrict__ A, const unsigned short* __restrict__ Bt,
    int K, int mode,
    const float* __restrict__ b0, const float* __restrict__ b1,
    const float* __restrict__ b2,
    unsigned short* __restrict__ oq, unsigned short* __restrict__ ok,
    unsigned short* __restrict__ ov, float* __restrict__ of) {
  __shared__ unsigned short lds[16384];  // A [128][64] @0, B [128][64] @16KB; swz byte^((row&7)<<4)
  int tid = threadIdx.x, w = tid >> 6, lane = tid & 63, lo = lane & 15, hi = lane >> 4;
  int wr = w >> 1, wc = w & 1;
  int m0 = blockIdx.x * 128, n0 = blockIdx.y * 128;
  f32x4 acc[4][4] = {};
  const char* Ab = (const char*)A;
  const char* Bb = (const char*)Bt;
  char* L = (char*)lds;

  for (int k0 = 0; k0 < K; k0 += 64) {
    // stage: linear LDS dest, inverse-swizzled global source (rule 21)
#pragma unroll
    for (int j = 0; j < 4; ++j) {
      int o = j * 4096 + w * 1024 + lane * 16;
      int r = o >> 7;
      int cb = (o & 127) ^ ((r & 7) << 4);
      gload16(L + j * 4096 + w * 1024,
              Ab + (size_t)(m0 + r) * K * 2 + k0 * 2 + cb);
    }
#pragma unroll
    for (int j = 0; j < 4; ++j) {
      int o = j * 4096 + w * 1024 + lane * 16;
      int r = o >> 7;
      int cb = (o & 127) ^ ((r & 7) << 4);
      gload16(L + 16384 + j * 4096 + w * 1024,
              Bb + (size_t)(n0 + r) * K * 2 + k0 * 2 + cb);
    }
    __syncthreads();
    short8 af[2][4], bf[2][4];
#pragma unroll
    for (int ks = 0; ks < 2; ++ks) {
#pragma unroll
      for (int i = 0; i < 4; ++i) {
        int row = wr * 64 + i * 16 + lo;
        af[ks][i] = *(const short8*)(L + ((row * 128 + ks * 64 + hi * 16) ^ ((row & 7) << 4)));
      }
#pragma unroll
      for (int j = 0; j < 4; ++j) {
        int row = wc * 64 + j * 16 + lo;
        bf[ks][j] = *(const short8*)(L + 16384 + ((row * 128 + ks * 64 + hi * 16) ^ ((row & 7) << 4)));
      }
    }
#pragma unroll
    for (int ks = 0; ks < 2; ++ks)
#pragma unroll
      for (int i = 0; i < 4; ++i)
#pragma unroll
        for (int j = 0; j < 4; ++j)
          acc[i][j] = __builtin_amdgcn_mfma_f32_16x16x32_bf16(af[ks][i], bf[ks][j], acc[i][j], 0, 0, 0);
    __syncthreads();
  }

  // epilogue; C/D layout: col = lane&15, row = (lane>>4)*4 + r  [verified m89]
  // Q scale folds 1/sqrt(128) AND log2(e) (attn softmax runs in exp2 domain)
#pragma unroll
  for (int i = 0; i < 4; ++i) {
    int mbase = m0 + wr * 64 + i * 16 + hi * 4;
#pragma unroll
    for (int j = 0; j < 4; ++j) {
      int n = n0 + wc * 64 + j * 16 + lo;
      if (mode == 0) {
        float bias;
        if (n < 2048) bias = b0[n];
        else if (n < 2560) bias = b1[n - 2048];
        else bias = b2[n - 2560];
#pragma unroll
        for (int r = 0; r < 4; ++r) {
          int mm = mbase + r;
          int b = mm >> 11, t = mm & 2047;
          float val = acc[i][j][r] + bias;
          if (n < 2048) {
            int h = n >> 7, d = n & 127;
            oq[(((size_t)(b * 16 + h)) * 2048 + t) * 128 + d] =
                f2bf(val * (0.08838834764831845f * 1.4426950408889634f));
          } else if (n < 2560) {
            int kvh = (n - 2048) >> 7, d = (n - 2048) & 127;
            ok[(((size_t)(b * 4 + kvh)) * 2048 + t) * 128 + d] = f2bf(val);
          } else {
            int kvh = (n - 2560) >> 7, d = (n - 2560) & 127;
            ov[(((size_t)(b * 4 + kvh)) * 128 + d) * 2048 + t] = f2bf(val);
          }
        }
      } else {
        float bias = b0[n];
#pragma unroll
        for (int r = 0; r < 4; ++r)
          of[(size_t)(mbase + r) * 2048 + n] = acc[i][j][r] + bias;
      }
    }
  }
}

// ---------------- flash attention: 32x32x16 MFMA, in-register P via permlane32_swap ----------------
// K LDS: [64 kv][128 d] rows 256B, swz byte^((kv&15)<<4)
// V LDS: [128 d][64 kv] rows 128B, swz byte^((d&7)<<4)
__device__ __forceinline__ void stageK(char* KLb, const char* kcb, int w, int lane, int t0) {
#pragma unroll
  for (int j = 0; j < 4; ++j) {
    int o = j * 4096 + w * 1024 + lane * 16;
    int row = o >> 8, col = o & 255;
    gload16(KLb + j * 4096 + w * 1024,
            kcb + (size_t)(t0 + row) * 256 + (col ^ ((row & 15) << 4)));
  }
}
__device__ __forceinline__ void stageV(char* VLb, const char* vcb, int w, int lane, int t0) {
#pragma unroll
  for (int j = 0; j < 4; ++j) {
    int o = j * 4096 + w * 1024 + lane * 16;
    int d = o >> 7, col = o & 127;
    gload16(VLb + j * 4096 + w * 1024,
            vcb + (size_t)d * 4096 + t0 * 2 + (col ^ ((d & 7) << 4)));
  }
}

// q[B,H,T,128] (pre-scaled by 1/sqrt(d)*log2e), k[B,KV,T,128], vt[B,KV,128,T]
// out attn[B,T,H*128] bf16; softmax in exp2 domain, defer-max THR=8
__global__ __launch_bounds__(256, 2) void attn_fwd(
    const unsigned short* __restrict__ q, const unsigned short* __restrict__ kg,
    const unsigned short* __restrict__ vtg, unsigned short* __restrict__ attn) {
  __shared__ unsigned short kbuf[16384];  // 2 x 16KB
  __shared__ unsigned short vbuf[16384];  // 2 x 16KB
  int tid = threadIdx.x, w = tid >> 6, lane = tid & 63;
  int l31 = lane & 31, hi5 = lane >> 5;
  int tq0 = blockIdx.x * 128, h = blockIdx.y, b = blockIdx.z, kvh = h >> 2;
  int qrow = tq0 + w * 32;

  // Q fragments (B-operand of swapped QK^T): col=q=l31, k=d = ds*16 + hi5*8 + e
  const unsigned short* qbase = q + ((size_t)(b * 16 + h)) * 2048 * 128;
  short8 qf[8];
#pragma unroll
  for (int ds_ = 0; ds_ < 8; ++ds_)
    qf[ds_] = *(const short8*)(qbase + (size_t)(qrow + l31) * 128 + ds_ * 16 + hi5 * 8);

  f32x16 oacc[4] = {};
  float mrow = -1e30f, lsum = 0.f;

  const char* kcb = (const char*)(kg + ((size_t)(b * 4 + kvh)) * 2048 * 128);
  const char* vcb = (const char*)(vtg + ((size_t)(b * 4 + kvh)) * 128 * 2048);
  char* KL = (char*)kbuf;
  char* VL = (char*)vbuf;

  stageK(KL, kcb, w, lane, 0);
  stageV(VL, vcb, w, lane, 0);
  __syncthreads();
  int buf = 0;

  for (int t0 = 0; t0 < 2048; t0 += 64) {
    if (t0 + 64 < 2048) {  // prefetch next chunk into other buffer
      stageK(KL + (buf ^ 1) * 16384, kcb, w, lane, t0 + 64);
      stageV(VL + (buf ^ 1) * 16384, vcb, w, lane, t0 + 64);
    }
    const char* KB = KL + buf * 16384;
    const char* VB = VL + buf * 16384;

    // S^T = K Q^T (32x32): s[f] covers kv = f*32 + (reg&3)+8*(reg>>2)+4*hi5, q = l31
    f32x16 s[2] = {};
    __builtin_amdgcn_s_setprio(1);
#pragma unroll
    for (int ds_ = 0; ds_ < 8; ++ds_) {
#pragma unroll
      for (int f = 0; f < 2; ++f) {
        int row = f * 32 + l31;
        short8 kf = *(const short8*)(KB + ((row * 256 + ds_ * 32 + hi5 * 16) ^ ((row & 15) << 4)));
        s[f] = __builtin_amdgcn_mfma_f32_32x32x16_bf16(kf, qf[ds_], s[f], 0, 0, 0);
      }
    }
    __builtin_amdgcn_s_setprio(0);

    // chunk-local max over this lane's 32 kv values (q = l31)
    float am = fmaxf(s[0][0], s[0][1]);
#pragma unroll
    for (int r = 2; r < 16; ++r) am = fmaxf(am, s[0][r]);
#pragma unroll
    for (int r = 0; r < 16; ++r) am = fmaxf(am, s[1][r]);

    // defer-max (log2 domain, THR=8)
    if (!__all(am <= mrow + 8.f)) {
      float ar = fmaxf(am, __shfl_xor(am, 32));
      float mnew = fmaxf(mrow, ar);
      float fsv = __builtin_amdgcn_exp2f(mrow - mnew);
      mrow = mnew;
      lsum *= fsv;
#pragma unroll
      for (int g = 0; g < 4; ++g)
#pragma unroll
        for (int r = 0; r < 4; ++r) {
          float fsr = __shfl(fsv, r + 8 * g + 4 * hi5);
#pragma unroll
          for (int db = 0; db < 4; ++db) oacc[db][4 * g + r] *= fsr;
        }
    }

    // P = exp2(S - m): pack pairs to bf16 (compiler cvt_pk), accumulate l
    unsigned pk01[2][4], pk23[2][4];
    float accl = 0.f;
#pragma unroll
    for (int f = 0; f < 2; ++f)
#pragma unroll
      for (int g = 0; g < 4; ++g) {
        float p0 = __builtin_amdgcn_exp2f(s[f][4 * g + 0] - mrow);
        float p1 = __builtin_amdgcn_exp2f(s[f][4 * g + 1] - mrow);
        float p2 = __builtin_amdgcn_exp2f(s[f][4 * g + 2] - mrow);
        float p3 = __builtin_amdgcn_exp2f(s[f][4 * g + 3] - mrow);
        pk01[f][g] = packbf2(p0, p1);
        pk23[f][g] = packbf2(p2, p3);
        accl += (p0 + p1) + (p2 + p3);
      }
    lsum += accl;

    // assemble PV A-frags in-register: pA[step][e] = P[q=l31][kv=16*step+8*hi5+e]
    short8 pA[4];
#pragma unroll
    for (int f = 0; f < 2; ++f)
#pragma unroll
      for (int p = 0; p < 2; ++p) {
        uint2v a01 = __builtin_amdgcn_permlane32_swap(pk01[f][2 * p], pk01[f][2 * p + 1], false, false);
        uint2v a23 = __builtin_amdgcn_permlane32_swap(pk23[f][2 * p], pk23[f][2 * p + 1], false, false);
        union { unsigned u[4]; short8 v; } pa;
        pa.u[0] = a01.x; pa.u[1] = a23.x; pa.u[2] = a01.y; pa.u[3] = a23.y;
        pA[2 * f + p] = pa.v;
      }

    // O += P V (32x32): oacc[db] col = d = db*32+l31, row = q
    __builtin_amdgcn_s_setprio(1);
#pragma unroll
    for (int db = 0; db < 4; ++db) {
      int d = db * 32 + l31;
      int sw = (d & 7) << 4;
#pragma unroll
      for (int step = 0; step < 4; ++step) {
        short8 vf = *(const short8*)(VB + ((d * 128 + step * 32 + hi5 * 16) ^ sw));
        oacc[db] = __builtin_amdgcn_mfma_f32_32x32x16_bf16(pA[step], vf, oacc[db], 0, 0, 0);
      }
    }
    __builtin_amdgcn_s_setprio(0);
    __syncthreads();
    buf ^= 1;
  }

  // epilogue: finish l across half-waves, write attn[b][t][h*128 + d]
  unsigned short* ob = attn + ((size_t)b * 2048) * 2048 + h * 128;
  float ls = lsum + __shfl_xor(lsum, 32);
  float linv = 1.0f / ls;
#pragma unroll
  for (int g = 0; g < 4; ++g)
#pragma unroll
    for (int r = 0; r < 4; ++r) {
      float lr = __shfl(linv, r + 8 * g + 4 * hi5);
      int t = qrow + r + 8 * g + 4 * hi5;
#pragma unroll
      for (int db = 0; db < 4; ++db)
        ob[(size_t)t * 2048 + db * 32 + l31] = f2bf(oacc[db][4 * g + r] * lr);
    }
}

extern "C" void kernel_launch(void* const* d_in, const int* in_sizes, int n_in,
                              void* d_out, int out_size, void* d_ws, size_t ws_size,
                              hipStream_t stream) {
  const float* x  = (const float*)d_in[0];
  // d_in[1] = mask (all-True, unused)
  const float* Wq = (const float*)d_in[2];
  const float* bq = (const float*)d_in[3];
  const float* Wk = (const float*)d_in[4];
  const float* bk = (const float*)d_in[5];
  const float* Wv = (const float*)d_in[6];
  const float* bv = (const float*)d_in[7];
  const float* Wo = (const float*)d_in[8];
  const float* bo = (const float*)d_in[9];
  float* out = (float*)d_out;

  char* ws = (char*)d_ws;
  unsigned short* xb    = (unsigned short*)(ws);                        // 16.78 MB
  unsigned short* wqkvT = (unsigned short*)(ws + 16777216);             // 12.58 MB
  unsigned short* woT   = (unsigned short*)(ws + 29360128);             //  8.39 MB
  unsigned short* qb    = (unsigned short*)(ws + 37748736);             // 16.78 MB
  unsigned short* kbw   = (unsigned short*)(ws + 54525952);             //  4.19 MB
  unsigned short* vtw   = (unsigned short*)(ws + 58720256);             //  4.19 MB
  unsigned short* attnb = (unsigned short*)(ws + 62914560);             // 16.78 MB

  cast_f32_bf16<<<dim3(4096), dim3(256), 0, stream>>>(x, xb, 1048576);
  trans_cast<<<dim3(64, 64), dim3(256), 0, stream>>>(Wq, wqkvT, 2048, 0);
  trans_cast<<<dim3(16, 64), dim3(256), 0, stream>>>(Wk, wqkvT, 512, 2048);
  trans_cast<<<dim3(16, 64), dim3(256), 0, stream>>>(Wv, wqkvT, 512, 2560);
  trans_cast<<<dim3(64, 64), dim3(256), 0, stream>>>(Wo, woT, 2048, 0);

  // fused QKV projection: M=4096, N=3072, K=2048
  gemm_bf16<<<dim3(32, 24), dim3(256), 0, stream>>>(
      xb, wqkvT, 2048, 0, bq, bk, bv, qb, kbw, vtw, nullptr);

  attn_fwd<<<dim3(16, 16, 2), dim3(256), 0, stream>>>(qb, kbw, vtw, attnb);

  // output projection: M=4096, N=2048, K=2048 -> fp32 out + bo
  gemm_bf16<<<dim3(32, 16), dim3(256), 0, stream>>>(
      attnb, woT, 2048, 1, bo, nullptr, nullptr, nullptr, nullptr, nullptr, out);
}